// Round 13
// baseline (166.946 us; speedup 1.0000x reference)
//
#include <hip/hip_runtime.h>
#include <hip/hip_bf16.h>

// AutoCorrelation layer: QKV proj (Q+K on a 256^2 8-phase counted-vmcnt MFMA
// schedule, bf16x2: Ahi*(Bhi+Blo); QT/KT stored bf16; V/OUT on dbuf-prefetch
// 128^2 with 8 waves) -> packed FFT cross-corr (radix-16 superstages; partials
// + reduce + ifft, NO atomics) -> single-pass bitonic top-8 + softmax ->
// delay-gather of V (bf16) -> output proj.  B=4, L=4096, D=512, H=8, Dh=64.

#define MiB (1024ull * 1024ull)

typedef __attribute__((ext_vector_type(8))) short bf16x8;
typedef __attribute__((ext_vector_type(4))) float f32x4;
static_assert(sizeof(bf16x8) == 16, "bf16x8 must be 16B");

__device__ __forceinline__ unsigned short f2bf(float f) {
  unsigned u = __float_as_uint(f);
  unsigned r = (u + 0x7FFFu + ((u >> 16) & 1u)) >> 16;  // RN-even
  return (unsigned short)r;
}
__device__ __forceinline__ float bf2f(unsigned short h) {
  return __uint_as_float(((unsigned)h) << 16);
}
// base-4 digit reversal of a 12-bit index (involution)
__device__ __forceinline__ int rev4_12(int x) {
  unsigned r = __brev((unsigned)x) >> 20;
  return (int)(((r & 0xAAAu) >> 1) | ((r & 0x555u) << 1));
}
// LDS pad: +1 float per 32 to break power-of-2 bank patterns
#define IDX(e) ((e) + ((e) >> 5))
#define LDSN (4095 + (4095 >> 5) + 1)

// XCD-aware bijective swizzle (nwg % 8 == 0): XCD x owns contiguous logical chunk.
__device__ __forceinline__ int xcd_swz(int bid, int cpx) {
  return (bid & 7) * cpx + (bid >> 3);
}

#define BARRIER() do { asm volatile("" ::: "memory"); __builtin_amdgcn_s_barrier(); asm volatile("" ::: "memory"); } while (0)
#define WAITV6() asm volatile("s_waitcnt vmcnt(6)" ::: "memory")

// ---------------- fused prep: x bf16 round + W hi/lo transposes + twiddle table -------
// blocks [0,8192): x_q AND x_kv round (1 float4 each per thread);
// [8192,8448): W transpose; [8448,8460): twiddles.
__global__ void prep_all(const float* __restrict__ xq, const float* __restrict__ xkv,
                         unsigned short* __restrict__ qhi, unsigned short* __restrict__ khi,
                         const float* __restrict__ W0, const float* __restrict__ W1,
                         const float* __restrict__ W2, const float* __restrict__ W3,
                         unsigned short* __restrict__ WT, float2* __restrict__ TWt, int n4) {
  __shared__ float t[64][65];
  int blk = blockIdx.x;
  int tid = threadIdx.x;
  if (blk < 8192) {
    int i = blk * 256 + tid;  // i < n4
    float4 vq = ((const float4*)xq)[i];
    float4 vk = ((const float4*)xkv)[i];
    ushort4 hq, hk;
    hq.x = f2bf(vq.x); hq.y = f2bf(vq.y); hq.z = f2bf(vq.z); hq.w = f2bf(vq.w);
    hk.x = f2bf(vk.x); hk.y = f2bf(vk.y); hk.z = f2bf(vk.z); hk.w = f2bf(vk.w);
    ((ushort4*)qhi)[i] = hq;
    ((ushort4*)khi)[i] = hk;
  } else if (blk < 8448) {
    int bx = blk - 8192;
    int w = bx >> 6, tile = bx & 63;
    int k0 = (tile >> 3) << 6, n0 = (tile & 7) << 6;
    const float* W = (w == 0) ? W0 : (w == 1) ? W1 : (w == 2) ? W2 : W3;
    unsigned short* hi = WT + (size_t)(2 * w) * 262144;
    unsigned short* lo = hi + 262144;
#pragma unroll
    for (int j = 0; j < 4; ++j) {
      int i = tid + (j << 8);
      int rr = i >> 4, c4 = (i & 15) << 2;
      float4 v = *(const float4*)&W[(size_t)(k0 + rr) * 512 + n0 + c4];
      t[rr][c4 + 0] = v.x; t[rr][c4 + 1] = v.y;
      t[rr][c4 + 2] = v.z; t[rr][c4 + 3] = v.w;
    }
    __syncthreads();
#pragma unroll
    for (int j = 0; j < 4; ++j) {
      int i = tid + (j << 8);
      int nn = i >> 4, k4 = (i & 15) << 2;
      ushort4 h, l;
      float f;
      f = t[k4 + 0][nn]; h.x = f2bf(f); l.x = f2bf(f - bf2f(h.x));
      f = t[k4 + 1][nn]; h.y = f2bf(f); l.y = f2bf(f - bf2f(h.y));
      f = t[k4 + 2][nn]; h.z = f2bf(f); l.z = f2bf(f - bf2f(h.z));
      f = t[k4 + 3][nn]; h.w = f2bf(f); l.w = f2bf(f - bf2f(h.w));
      size_t o = (size_t)(n0 + nn) * 512 + k0 + k4;
      *(ushort4*)(hi + o) = h;
      *(ushort4*)(lo + o) = l;
    }
  } else {
    int r = (blk - 8448) * 256 + tid;
    if (r < 3072) {
      double a = -2.0 * 3.14159265358979323846 * (double)r / 4096.0;
      TWt[r] = make_float2((float)cos(a), (float)sin(a));
    }
  }
}

// ---------------- fused Q+K GEMM: 256^2 tile, 8-wave, 4-phase/K-tile, counted vmcnt ----
// bf16x2: 16 K-tiles (v 0..7 = Ahi*Bhi, v 8..15 = Ahi*Blo), K'=1024. Output bf16.
__global__ __launch_bounds__(512, 2)
void qk_gemm8(const unsigned short* __restrict__ AqHi, const unsigned short* __restrict__ AkvHi,
              const unsigned short* __restrict__ WT,
              const float* __restrict__ bq, const float* __restrict__ bk,
              unsigned short* __restrict__ QT, unsigned short* __restrict__ KT) {
  __shared__ __align__(16) char lds[131072];
  int tid = threadIdx.x;
  int lane = tid & 63, wv = tid >> 6;
  int wm = wv >> 2, wn = wv & 3;

  int sw = xcd_swz(blockIdx.x, 32);  // 256 wgs
  int op = sw >> 7;                  // 0 = Q, 1 = K
  int r = sw & 127;
  int m0 = (r >> 1) << 8;            // 64 M-tiles
  int n0 = (r & 1) << 8;             // 2 N-tiles

  const unsigned short* Ahi = op ? AkvHi : AqHi;
  const unsigned short* Bhi = WT + (op ? 2 * 262144 : 0);
  const unsigned short* Blo = Bhi + 262144;
  const float* bias = op ? bk : bq;
  unsigned short* C = op ? KT : QT;

  int aoff0 = ((lane & 15) << 7) + ((((lane >> 4) + 0) ^ (lane & 7)) << 4);  // ks=0
  int aoff1 = ((lane & 15) << 7) + ((((lane >> 4) + 4) ^ (lane & 7)) << 4);  // ks=1
  int src_row = tid >> 3;
  int src_col = (tid & 7) ^ (src_row & 7);

  f32x4 acc[8][4];
  const f32x4 zz = {0.f, 0.f, 0.f, 0.f};
#pragma unroll
  for (int i = 0; i < 8; ++i)
#pragma unroll
    for (int j = 0; j < 4; ++j) acc[i][j] = zz;

  auto APTR = [&](int v) {
    return Ahi + (size_t)m0 * 512 + ((v & 7) << 6);
  };
  auto BPTR = [&](int v) {
    const unsigned short* p = (v >= 8) ? Blo : Bhi;
    return p + (size_t)n0 * 512 + ((v & 7) << 6);
  };
  auto STAGE = [&](const unsigned short* gbase, int R0, int ldsOff) {
    const unsigned short* ga = gbase + (size_t)(R0 + src_row) * 512 + (src_col << 3);
    char* la = lds + ldsOff + (R0 << 7) + (wv << 10);
    __builtin_amdgcn_global_load_lds((const __attribute__((address_space(1))) void*)ga,
                                     (__attribute__((address_space(3))) void*)la, 16, 0, 0);
  };
#define RDA(o, mi, ks) (*(const bf16x8*)(lds + (o) + (wm << 14) + ((mi) << 11) + aoff##ks))
#define RDB(o, ni, ks) (*(const bf16x8*)(lds + (o) + 32768 + (wn << 13) + ((ni) << 11) + aoff##ks))
#define MFMA_PAIR(mi0, A0, A1)                                                              \
  __builtin_amdgcn_s_setprio(1);                                                            \
  _Pragma("unroll") for (int ks = 0; ks < 2; ++ks) {                                        \
    _Pragma("unroll") for (int ni = 0; ni < 4; ++ni) {                                      \
      acc[mi0][ni] = __builtin_amdgcn_mfma_f32_16x16x32_bf16(A0[ks], b[ni][ks], acc[mi0][ni], 0, 0, 0);          \
      acc[mi0 + 1][ni] = __builtin_amdgcn_mfma_f32_16x16x32_bf16(A1[ks], b[ni][ks], acc[mi0 + 1][ni], 0, 0, 0);  \
    }                                                                                       \
  }                                                                                         \
  __builtin_amdgcn_s_setprio(0)

  STAGE(BPTR(0), 0, 32768);   STAGE(BPTR(0), 64, 32768);
  STAGE(BPTR(0), 128, 32768); STAGE(BPTR(0), 192, 32768);
  STAGE(APTR(0), 0, 0);       STAGE(APTR(0), 64, 0);
  STAGE(APTR(0), 128, 0);     STAGE(APTR(0), 192, 0);
  STAGE(BPTR(1), 0, 65536 + 32768);   STAGE(BPTR(1), 64, 65536 + 32768);
  STAGE(BPTR(1), 128, 65536 + 32768); STAGE(BPTR(1), 192, 65536 + 32768);
  STAGE(APTR(1), 0, 65536);           STAGE(APTR(1), 128, 65536);
  WAITV6();
  BARRIER();

  for (int t = 0; t < 16; ++t) {
    int o = (t & 1) << 16;
    int on = o ^ 65536;
    int t1 = (t + 1 < 16) ? t + 1 : 15;
    int t2 = (t + 2 < 16) ? t + 2 : 15;
    const unsigned short* a1p = APTR(t1);
    const unsigned short* a2p = APTR(t2);
    const unsigned short* b2p = BPTR(t2);

    bf16x8 b[4][2], aA[2][2];
#pragma unroll
    for (int ni = 0; ni < 4; ++ni) { b[ni][0] = RDB(o, ni, 0); b[ni][1] = RDB(o, ni, 1); }
    aA[0][0] = RDA(o, 0, 0); aA[0][1] = RDA(o, 0, 1);
    aA[1][0] = RDA(o, 1, 0); aA[1][1] = RDA(o, 1, 1);
    STAGE(a1p, 64, on); STAGE(a1p, 192, on);
    BARRIER();
    MFMA_PAIR(0, aA[0], aA[1]);
    BARRIER();

    aA[0][0] = RDA(o, 2, 0); aA[0][1] = RDA(o, 2, 1);
    aA[1][0] = RDA(o, 3, 0); aA[1][1] = RDA(o, 3, 1);
    STAGE(b2p, 0, o + 32768); STAGE(b2p, 64, o + 32768);
    BARRIER();
    MFMA_PAIR(2, aA[0], aA[1]);
    BARRIER();

    aA[0][0] = RDA(o, 4, 0); aA[0][1] = RDA(o, 4, 1);
    aA[1][0] = RDA(o, 5, 0); aA[1][1] = RDA(o, 5, 1);
    STAGE(b2p, 128, o + 32768); STAGE(b2p, 192, o + 32768);
    BARRIER();
    MFMA_PAIR(4, aA[0], aA[1]);
    BARRIER();

    aA[0][0] = RDA(o, 6, 0); aA[0][1] = RDA(o, 6, 1);
    aA[1][0] = RDA(o, 7, 0); aA[1][1] = RDA(o, 7, 1);
    STAGE(a2p, 0, o); STAGE(a2p, 128, o);
    BARRIER();
    MFMA_PAIR(6, aA[0], aA[1]);
    WAITV6();
    BARRIER();
  }
#undef RDA
#undef RDB
#undef MFMA_PAIR

  // epilogue: bf16 C[(b*512+col)*4096 + t], ushort4 (8B) per lane
#pragma unroll
  for (int mi = 0; mi < 8; ++mi) {
    int mrow0 = m0 + (wm << 7) + (mi << 4) + ((lane >> 4) << 2);
    int bq_ = mrow0 >> 12;
    int t0 = mrow0 & 4095;
#pragma unroll
    for (int ni = 0; ni < 4; ++ni) {
      int col = n0 + (wn << 6) + (ni << 4) + (lane & 15);
      float bv = bias[col];
      f32x4 v = acc[mi][ni];
      ushort4 hv;
      hv.x = f2bf(v.x + bv); hv.y = f2bf(v.y + bv);
      hv.z = f2bf(v.z + bv); hv.w = f2bf(v.w + bv);
      *(ushort4*)&C[((size_t)(bq_ * 512 + col)) * 4096 + t0] = hv;
    }
  }
}

// ---------------- generic GEMM: V (mode 1, bf16 out) and OUT (mode 2, f32 out) ---------
// 128^2 tile, 512 threads / 8 waves (2x4), dbuf LDS + stage-next-before-compute.
// 2 blocks/CU (64 KB LDS) -> 4 waves/SIMD for latency hiding.
__global__ __launch_bounds__(512, 4)
void gemm_bf16(const unsigned short* __restrict__ Ahi,
               const unsigned short* __restrict__ Bhi,
               const float* __restrict__ bias, float* __restrict__ Cf,
               unsigned short* __restrict__ Ch, int mode) {
  __shared__ short As[2][128 * 64];
  __shared__ short Bs[2][128 * 64];
  int bx = xcd_swz(blockIdx.x, 64);  // 512 wgs
  int bm = bx >> 2, bn = bx & 3;
  int m0 = bm << 7, n0 = bn << 7;
  int tid = threadIdx.x;
  int lane = tid & 63, wv = tid >> 6;
  int wm = wv >> 2, wn = wv & 3;  // 2 x 4 waves; per wave 64 rows x 32 cols

  const f32x4 zz = {0.f, 0.f, 0.f, 0.f};
  f32x4 acc[4][2];
#pragma unroll
  for (int i = 0; i < 4; ++i)
#pragma unroll
    for (int j = 0; j < 2; ++j) acc[i][j] = zz;

  int srow = tid >> 3;          // 0..63
  int sk = (tid & 7) << 3;
  auto STAGE = [&](int ks, int buf) {
    int kb = ks << 6;
#pragma unroll
    for (int i = 0; i < 2; ++i) {
      int r = (i << 6) + srow;
      const unsigned short* ga = Ahi + (size_t)(m0 + r) * 512 + kb + sk;
      const unsigned short* gb = Bhi + (size_t)(n0 + r) * 512 + kb + sk;
      char* la = (char*)As[buf] + (i << 13) + (wv << 10);
      char* lb = (char*)Bs[buf] + (i << 13) + (wv << 10);
      __builtin_amdgcn_global_load_lds((const __attribute__((address_space(1))) void*)ga,
                                       (__attribute__((address_space(3))) void*)la, 16, 0, 0);
      __builtin_amdgcn_global_load_lds((const __attribute__((address_space(1))) void*)gb,
                                       (__attribute__((address_space(3))) void*)lb, 16, 0, 0);
    }
  };

  STAGE(0, 0);
  __syncthreads();
  for (int ks = 0; ks < 8; ++ks) {
    int buf = ks & 1;
    if (ks < 7) STAGE(ks + 1, buf ^ 1);
#pragma unroll
    for (int kk = 0; kk < 2; ++kk) {
      bf16x8 af[4], bfr[2];
      int krd = (kk << 5) + ((lane >> 4) << 3);
#pragma unroll
      for (int mi = 0; mi < 4; ++mi)
        af[mi] = *(const bf16x8*)&As[buf][((wm << 6) + (mi << 4) + (lane & 15)) * 64 + krd];
#pragma unroll
      for (int ni = 0; ni < 2; ++ni)
        bfr[ni] = *(const bf16x8*)&Bs[buf][((wn << 5) + (ni << 4) + (lane & 15)) * 64 + krd];
#pragma unroll
      for (int mi = 0; mi < 4; ++mi)
#pragma unroll
        for (int ni = 0; ni < 2; ++ni)
          acc[mi][ni] = __builtin_amdgcn_mfma_f32_16x16x32_bf16(af[mi], bfr[ni], acc[mi][ni], 0, 0, 0);
    }
    __syncthreads();  // drains ks+1 loads; protects buf reuse at ks+2
  }

#pragma unroll
  for (int mi = 0; mi < 4; ++mi) {
    int mrow0 = m0 + (wm << 6) + (mi << 4) + ((lane >> 4) << 2);
    int bq_ = mrow0 >> 12;
    int t0 = mrow0 & 4095;
#pragma unroll
    for (int ni = 0; ni < 2; ++ni) {
      int col = n0 + (wn << 5) + (ni << 4) + (lane & 15);
      float bv = bias[col];
      f32x4 v = acc[mi][ni];
      v.x += bv; v.y += bv; v.z += bv; v.w += bv;
      if (mode == 1) {
        // V layout (bf16): Ch[((b*8+h)*4096+t)*64 + d]
        size_t base = (size_t)(bq_ * 8 + (col >> 6)) * 4096;
        int d = col & 63;
        Ch[(base + t0 + 0) * 64 + d] = f2bf(v.x);
        Ch[(base + t0 + 1) * 64 + d] = f2bf(v.y);
        Ch[(base + t0 + 2) * 64 + d] = f2bf(v.z);
        Ch[(base + t0 + 3) * 64 + d] = f2bf(v.w);
      } else {
        Cf[(size_t)(mrow0 + 0) * 512 + col] = v.x;
        Cf[(size_t)(mrow0 + 1) * 512 + col] = v.y;
        Cf[(size_t)(mrow0 + 2) * 512 + col] = v.z;
        Cf[(size_t)(mrow0 + 3) * 512 + col] = v.w;
      }
    }
  }
}

// ---------------- FFT: radix-16 superstages (stage pairs fused in registers) ----------
__device__ __forceinline__ void r4(float& x0r, float& x0i, float& x1r, float& x1i,
                                   float& x2r, float& x2i, float& x3r, float& x3i,
                                   float2 w1, float2 w2, float2 w3) {
  float Ar = x0r + x2r, Ai = x0i + x2i;
  float Br = x0r - x2r, Bi = x0i - x2i;
  float Cr = x1r + x3r, Ci = x1i + x3i;
  float Dr = x1i - x3i, Di = x3r - x1r;  // -i*(x1-x3)
  x0r = Ar + Cr; x0i = Ai + Ci;
  float tr = Br + Dr, ti = Bi + Di;
  x1r = tr * w1.x - ti * w1.y; x1i = tr * w1.y + ti * w1.x;
  tr = Ar - Cr; ti = Ai - Ci;
  x2r = tr * w2.x - ti * w2.y; x2i = tr * w2.y + ti * w2.x;
  tr = Br - Dr; ti = Bi - Di;
  x3r = tr * w3.x - ti * w3.y; x3i = tr * w3.y + ti * w3.x;
}

__device__ __forceinline__ void fft16_superstages(float* re, float* im,
                                                  const float2* __restrict__ TW,
                                                  int u, bool active) {
#pragma unroll
  for (int ss = 0; ss < 3; ++ss) {
    const int lm = 10 - 4 * ss;      // 10, 6, 2
    const int m = 1 << lm;
    const int m4 = m >> 2;
    const int stw = 1 << (4 * ss);   // 1, 16, 256
    const int stw4 = stw << 2;
    if (active) {
      int jj = u & (m4 - 1);
      int g = u >> (lm - 2);
      int base = (g << (lm + 2)) + jj;
      float xr[4][4], xi[4][4];
#pragma unroll
      for (int a = 0; a < 4; ++a)
#pragma unroll
        for (int b = 0; b < 4; ++b) {
          int p = IDX(base + a * m + b * m4);
          xr[a][b] = re[p]; xi[a][b] = im[p];
        }
#pragma unroll
      for (int b = 0; b < 4; ++b) {
        int j1 = (b * m4 + jj) * stw;
        float2 w1 = TW[j1], w2 = TW[2 * j1], w3 = TW[3 * j1];
        r4(xr[0][b], xi[0][b], xr[1][b], xi[1][b], xr[2][b], xi[2][b], xr[3][b], xi[3][b], w1, w2, w3);
      }
      {
        int j2 = jj * stw4;
        float2 v1 = TW[j2], v2 = TW[2 * j2], v3 = TW[3 * j2];
#pragma unroll
        for (int a = 0; a < 4; ++a)
          r4(xr[a][0], xi[a][0], xr[a][1], xi[a][1], xr[a][2], xi[a][2], xr[a][3], xi[a][3], v1, v2, v3);
      }
#pragma unroll
      for (int a = 0; a < 4; ++a)
#pragma unroll
        for (int b = 0; b < 4; ++b) {
          int p = IDX(base + a * m + b * m4);
          re[p] = xr[a][b]; im[p] = xi[a][b];
        }
    }
    __syncthreads();
  }
}

// Packed FFT of z = q + i*k per (b,h,d) with bf16 Q/K inputs; one wg (512 thr)
// handles 4 d's as 2 rounds of 2 CONCURRENT FFTs (256 units each, wave-uniform).
// 512 wgs = 32 bh x 16 parts; NO atomics.
__global__ __launch_bounds__(512, 2)
void fft_corr(const unsigned short* __restrict__ QT, const unsigned short* __restrict__ KT,
              const float2* __restrict__ TW, float* __restrict__ PpartRe,
              float* __restrict__ PpartIm) {
  __shared__ float re[2][LDSN];
  __shared__ float im[2][LDSN];
  int wg = blockIdx.x;
  int bh = wg >> 4;
  int d0 = (wg & 15) << 2;
  int tid = threadIdx.x;
  const unsigned short* qb = QT + (size_t)bh * 64 * 4096;
  const unsigned short* kb = KT + (size_t)bh * 64 * 4096;
  float accR[8], accI[8];
#pragma unroll
  for (int j = 0; j < 8; ++j) { accR[j] = 0.f; accI[j] = 0.f; }
  for (int rr = 0; rr < 2; ++rr) {
    if (rr) __syncthreads();  // prior extraction reads done
#pragma unroll
    for (int ff = 0; ff < 2; ++ff) {
      const unsigned short* q8 = qb + (size_t)(d0 + 2 * rr + ff) * 4096;
      const unsigned short* k8 = kb + (size_t)(d0 + 2 * rr + ff) * 4096;
      uint4 qraw = *(const uint4*)(q8 + ((size_t)tid << 3));  // 8 bf16
      uint4 kraw = *(const uint4*)(k8 + ((size_t)tid << 3));
      int e = tid << 3;
      re[ff][IDX(e + 0)] = bf2f((unsigned short)(qraw.x & 0xFFFF));
      re[ff][IDX(e + 1)] = bf2f((unsigned short)(qraw.x >> 16));
      re[ff][IDX(e + 2)] = bf2f((unsigned short)(qraw.y & 0xFFFF));
      re[ff][IDX(e + 3)] = bf2f((unsigned short)(qraw.y >> 16));
      re[ff][IDX(e + 4)] = bf2f((unsigned short)(qraw.z & 0xFFFF));
      re[ff][IDX(e + 5)] = bf2f((unsigned short)(qraw.z >> 16));
      re[ff][IDX(e + 6)] = bf2f((unsigned short)(qraw.w & 0xFFFF));
      re[ff][IDX(e + 7)] = bf2f((unsigned short)(qraw.w >> 16));
      im[ff][IDX(e + 0)] = bf2f((unsigned short)(kraw.x & 0xFFFF));
      im[ff][IDX(e + 1)] = bf2f((unsigned short)(kraw.x >> 16));
      im[ff][IDX(e + 2)] = bf2f((unsigned short)(kraw.y & 0xFFFF));
      im[ff][IDX(e + 3)] = bf2f((unsigned short)(kraw.y >> 16));
      im[ff][IDX(e + 4)] = bf2f((unsigned short)(kraw.z & 0xFFFF));
      im[ff][IDX(e + 5)] = bf2f((unsigned short)(kraw.z >> 16));
      im[ff][IDX(e + 6)] = bf2f((unsigned short)(kraw.w & 0xFFFF));
      im[ff][IDX(e + 7)] = bf2f((unsigned short)(kraw.w >> 16));
    }
    __syncthreads();
    // wave-uniform FFT split: waves 0-3 -> fft 0, waves 4-7 -> fft 1
    fft16_superstages(re[tid >> 8], im[tid >> 8], TW, tid & 255, true);
#pragma unroll
    for (int ff = 0; ff < 2; ++ff) {
#pragma unroll
      for (int j = 0; j < 8; ++j) {
        int p = tid + (j << 9);
        int f = rev4_12(p);
        int fn = (4096 - f) & 4095;
        int pn = rev4_12(fn);
        float zr = re[ff][IDX(p)], zi = im[ff][IDX(p)];
        float wr = re[ff][IDX(pn)], wi = im[ff][IDX(pn)];
        float qre = 0.5f * (zr + wr), qim = 0.5f * (zi - wi);
        float kre = 0.5f * (zi + wi), kim = 0.5f * (wr - zr);
        accR[j] += qre * kre + qim * kim;   // Re(Qf*conj(Kf))
        accI[j] += qim * kre - qre * kim;   // Im(Qf*conj(Kf))
      }
    }
  }
  float* pR = PpartRe + (size_t)wg * 4096;
  float* pI = PpartIm + (size_t)wg * 4096;
#pragma unroll
  for (int j = 0; j < 8; ++j) {
    int p = tid + (j << 9);
    pR[p] = accR[j];
    pI[p] = accI[j];
  }
}

// Reduce 16 partials per (b,h) -> Psum, float4. Grid 128 = 32 bh x 4 chunks of 1024 p.
__global__ void reduce_p(const float* __restrict__ PpartRe, const float* __restrict__ PpartIm,
                         float* __restrict__ PsumRe, float* __restrict__ PsumIm) {
  int wg = blockIdx.x;
  int bh = wg >> 2;
  int p4 = ((wg & 3) << 8) + threadIdx.x;  // float4 index 0..1023
  const float4* bR = (const float4*)(PpartRe + (size_t)bh * 16 * 4096);
  const float4* bI = (const float4*)(PpartIm + (size_t)bh * 16 * 4096);
  float4 sr = make_float4(0.f, 0.f, 0.f, 0.f);
  float4 si = make_float4(0.f, 0.f, 0.f, 0.f);
#pragma unroll
  for (int part = 0; part < 16; ++part) {
    float4 a = bR[part * 1024 + p4];
    float4 b = bI[part * 1024 + p4];
    sr.x += a.x; sr.y += a.y; sr.z += a.z; sr.w += a.w;
    si.x += b.x; si.y += b.y; si.z += b.z; si.w += b.w;
  }
  ((float4*)(PsumRe + (size_t)bh * 4096))[p4] = sr;
  ((float4*)(PsumIm + (size_t)bh * 4096))[p4] = si;
}

// Inverse FFT via conj + forward DIF (radix-16); corr(tau=rev4(p)) = re[p]/(4096*64).
// Single-pass top-8: pack (value,tau) -> ordered u64 key; per-thread sort-8;
// 6-level shfl_xor butterfly with Batcher half-cleaner; final 8-list serial merge.
__global__ __launch_bounds__(512, 1)
void ifft_topk(const float* __restrict__ PsumRe, const float* __restrict__ PsumIm,
               const float2* __restrict__ TW, float* __restrict__ attnW, int* __restrict__ delays) {
  __shared__ float re[LDSN];
  __shared__ float im[LDSN];
  __shared__ unsigned long long sh[8][8];
  int bh = blockIdx.x, tid = threadIdx.x;
  int lane = tid & 63, wv = tid >> 6;
  const float4* pr4 = (const float4*)(PsumRe + (size_t)bh * 4096);
  const float4* pi4 = (const float4*)(PsumIm + (size_t)bh * 4096);
#pragma unroll
  for (int i = 0; i < 2; ++i) {
    int e4 = tid + (i << 9);
    float4 a = pr4[e4], b = pi4[e4];
    int fb = rev4_12(e4 << 2);  // rev4 of (e4*4 + j) = fb | (j<<10)
    re[IDX(fb + 0 * 1024)] = a.x; im[IDX(fb + 0 * 1024)] = -b.x;
    re[IDX(fb + 1 * 1024)] = a.y; im[IDX(fb + 1 * 1024)] = -b.y;
    re[IDX(fb + 2 * 1024)] = a.z; im[IDX(fb + 2 * 1024)] = -b.z;
    re[IDX(fb + 3 * 1024)] = a.w; im[IDX(fb + 3 * 1024)] = -b.w;
  }
  __syncthreads();
  fft16_superstages(re, im, TW, tid & 255, tid < 256);

  // build per-thread desc-sorted 8 keys (value desc, tau asc on ties)
  unsigned long long k[8];
#pragma unroll
  for (int i = 0; i < 8; ++i) {
    int p = tid + (i << 9);
    float v = re[IDX(p)];
    int tau = rev4_12(p);
    unsigned u = __float_as_uint(v);
    unsigned s = u ^ (unsigned)(((int)u >> 31) | 0x80000000);  // order-preserving map
    k[i] = ((unsigned long long)s << 12) | (unsigned)(4095 - tau);
  }
#define CSWAP(a, b) { if (k[a] < k[b]) { unsigned long long t_ = k[a]; k[a] = k[b]; k[b] = t_; } }
  // insertion network (28 comparators), descending
#pragma unroll
  for (int i = 1; i < 8; ++i)
#pragma unroll
    for (int j = 8 - 1; j >= 1; --j)
      if (j <= i) CSWAP(j - 1, j);
  // butterfly merge across 64 lanes: keep top-8 of pairwise unions
#pragma unroll
  for (int off = 1; off < 64; off <<= 1) {
    unsigned long long b[8];
#pragma unroll
    for (int i = 0; i < 8; ++i)
      b[i] = (unsigned long long)__shfl_xor((long long)k[i], off);
#pragma unroll
    for (int i = 0; i < 8; ++i) {
      unsigned long long m = b[7 - i];        // half-cleaner: max(A[i], B[7-i])
      k[i] = (k[i] > m) ? k[i] : m;
    }
    // bitonic clean (descending), distances 4, 2, 1
#pragma unroll
    for (int d = 4; d > 0; d >>= 1)
#pragma unroll
      for (int i = 0; i < 8; ++i)
        if ((i & d) == 0 && (i ^ d) < 8) CSWAP(i, i + d);
  }
#undef CSWAP
  if (lane == 0) {
#pragma unroll
    for (int i = 0; i < 8; ++i) sh[wv][i] = k[i];
  }
  __syncthreads();
  if (tid == 0) {
    const float SC = 1.0f / 262144.0f;  // 1/(L*Dh)
    int idx[8] = {0, 0, 0, 0, 0, 0, 0, 0};
    float topv[8]; int topi[8];
#pragma unroll
    for (int pass = 0; pass < 8; ++pass) {
      int bw = 0;
      unsigned long long bk = sh[0][idx[0]];
#pragma unroll
      for (int w = 1; w < 8; ++w) {
        unsigned long long c = sh[w][idx[w]];
        if (c > bk) { bk = c; bw = w; }
      }
      idx[bw]++;
      unsigned s = (unsigned)(bk >> 12);
      unsigned u = (s & 0x80000000u) ? (s ^ 0x80000000u) : ~s;
      topv[pass] = __uint_as_float(u) * SC;
      topi[pass] = 4095 - (int)(bk & 4095u);
    }
    float mx = topv[0];  // pass 0 = global max
    float ex[8], ssum = 0.f;
    for (int q = 0; q < 8; ++q) { ex[q] = expf(topv[q] - mx); ssum += ex[q]; }
    float inv = 1.0f / ssum;
    for (int q = 0; q < 8; ++q) {
      attnW[bh * 8 + q] = ex[q] * inv;
      delays[bh * 8 + q] = topi[q];
    }
  }
}

// out[b,h,t,:] = sum_k attn_k * V[b,h,(t-d_k)%L,:] (V bf16); write bf16 A for OUT gemm.
// Grid 4096 = 32 bh x 128 t-chunks of 32; thread handles 8 d's (16B loads/stores).
__global__ void gather_av(const unsigned short* __restrict__ Vh, const float* __restrict__ attnW,
                          const int* __restrict__ delays, unsigned short* __restrict__ Ahi) {
  int blk = blockIdx.x;
  int bh = blk >> 7, tb = blk & 127;
  int tid = threadIdx.x;
  int tt = tid >> 3, d8 = tid & 7;
  int t = (tb << 5) + tt;
  const unsigned short* Vb = Vh + (size_t)bh * 4096 * 64 + (d8 << 3);
  float w[8]; int dl[8];
#pragma unroll
  for (int kk = 0; kk < 8; ++kk) { w[kk] = attnW[bh * 8 + kk]; dl[kk] = delays[bh * 8 + kk]; }
  float a0 = 0.f, a1 = 0.f, a2 = 0.f, a3 = 0.f, a4 = 0.f, a5 = 0.f, a6 = 0.f, a7 = 0.f;
#pragma unroll
  for (int kk = 0; kk < 8; ++kk) {
    int row = (t - dl[kk]) & 4095;
    uint4 raw = *(const uint4*)(Vb + row * 64);
    float wk = w[kk];
    a0 += wk * bf2f((unsigned short)(raw.x & 0xFFFF));
    a1 += wk * bf2f((unsigned short)(raw.x >> 16));
    a2 += wk * bf2f((unsigned short)(raw.y & 0xFFFF));
    a3 += wk * bf2f((unsigned short)(raw.y >> 16));
    a4 += wk * bf2f((unsigned short)(raw.z & 0xFFFF));
    a5 += wk * bf2f((unsigned short)(raw.z >> 16));
    a6 += wk * bf2f((unsigned short)(raw.w & 0xFFFF));
    a7 += wk * bf2f((unsigned short)(raw.w >> 16));
  }
  int b = bh >> 3, h = bh & 7;
  size_t o = ((size_t)((b << 12) + t)) * 512 + (h << 6) + (d8 << 3);
  uint4 out;
  out.x = (unsigned)f2bf(a0) | ((unsigned)f2bf(a1) << 16);
  out.y = (unsigned)f2bf(a2) | ((unsigned)f2bf(a3) << 16);
  out.z = (unsigned)f2bf(a4) | ((unsigned)f2bf(a5) << 16);
  out.w = (unsigned)f2bf(a6) | ((unsigned)f2bf(a7) << 16);
  *(uint4*)(Ahi + o) = out;
}

// ---------------- orchestration ----------------
extern "C" void kernel_launch(void* const* d_in, const int* in_sizes, int n_in,
                              void* d_out, int out_size, void* d_ws, size_t ws_size,
                              hipStream_t stream) {
  (void)in_sizes; (void)n_in; (void)out_size; (void)ws_size;
  const float* x_q = (const float*)d_in[0];
  const float* x_kv = (const float*)d_in[1];
  const float* Wq = (const float*)d_in[2];
  const float* bq = (const float*)d_in[3];
  const float* Wk = (const float*)d_in[4];
  const float* bk = (const float*)d_in[5];
  const float* Wv = (const float*)d_in[6];
  const float* bv = (const float*)d_in[7];
  const float* Wo = (const float*)d_in[8];
  const float* bo = (const float*)d_in[9];
  float* out = (float*)d_out;
  char* ws = (char*)d_ws;

  // workspace layout (~137.1 MiB)
  unsigned short* AqHi  = (unsigned short*)(ws + 0 * MiB);
  unsigned short* Vbuf16 = (unsigned short*)(ws + 0 * MiB);  // after qk_gemm8
  unsigned short* AkvHi = (unsigned short*)(ws + 36 * MiB);
  float* PpartRe = (float*)(ws + 36 * MiB);                  // after v_gemm
  float* PpartIm = (float*)(ws + 52 * MiB);
  unsigned short* Aattn = (unsigned short*)(ws + 36 * MiB);  // after reduce_p
  unsigned short* WTb   = (unsigned short*)(ws + 68 * MiB);
  unsigned short* QT    = (unsigned short*)(ws + 72 * MiB);
  unsigned short* KT    = (unsigned short*)(ws + 104 * MiB);
  float* PsumRe = (float*)(ws + 72 * MiB);
  float* PsumIm = (float*)(ws + 73 * MiB);
  float* attnW = (float*)(ws + 137 * MiB);
  int*   delays = (int*)(ws + 137 * MiB + 4096);
  float2* TW   = (float2*)(ws + 137 * MiB + 8192);

  int n4 = (16384 * 512) / 4;
  prep_all<<<dim3(8460), dim3(256), 0, stream>>>(x_q, x_kv, AqHi, AkvHi,
                                                 Wq, Wk, Wv, Wo, WTb, TW, n4);

  // Q and K projections fused, 256^2 8-phase bf16x2 (256 wgs x 512 thr).
  qk_gemm8<<<dim3(256), dim3(512), 0, stream>>>(AqHi, AkvHi, WTb, bq, bk, QT, KT);
  gemm_bf16<<<dim3(512), dim3(512), 0, stream>>>(AkvHi, WTb + 4 * 262144, bv, nullptr, Vbuf16, 1);

  fft_corr<<<dim3(512), dim3(512), 0, stream>>>(QT, KT, TW, PpartRe, PpartIm);
  reduce_p<<<dim3(128), dim3(256), 0, stream>>>(PpartRe, PpartIm, PsumRe, PsumIm);
  ifft_topk<<<dim3(32), dim3(512), 0, stream>>>(PsumRe, PsumIm, TW, attnW, delays);
  gather_av<<<dim3(4096), dim3(256), 0, stream>>>(Vbuf16, attnW, delays, Aattn);

  // out = gathered @ Wo + bo (plain bf16 -> f32 out)
  gemm_bf16<<<dim3(512), dim3(512), 0, stream>>>(Aattn, WTb + 6 * 262144, bo, out, nullptr, 2);
}

// Round 14
// 164.189 us; speedup vs baseline: 1.0168x; 1.0168x over previous
//
#include <hip/hip_runtime.h>
#include <hip/hip_bf16.h>

// AutoCorrelation layer: QKV proj (Q+K on a 256^2 8-phase counted-vmcnt MFMA
// schedule, bf16x2: Ahi*(Bhi+Blo); QT/KT stored bf16; V/OUT on dbuf-prefetch
// 128^2, 256 thr / 4 waves) -> packed FFT cross-corr (radix-16 superstages;
// partials + reduce + ifft, NO atomics) -> single-pass bitonic top-8 + softmax
// -> delay-gather of V (bf16) -> output proj.  B=4, L=4096, D=512, H=8, Dh=64.

#define MiB (1024ull * 1024ull)

typedef __attribute__((ext_vector_type(8))) short bf16x8;
typedef __attribute__((ext_vector_type(4))) float f32x4;
static_assert(sizeof(bf16x8) == 16, "bf16x8 must be 16B");

__device__ __forceinline__ unsigned short f2bf(float f) {
  unsigned u = __float_as_uint(f);
  unsigned r = (u + 0x7FFFu + ((u >> 16) & 1u)) >> 16;  // RN-even
  return (unsigned short)r;
}
__device__ __forceinline__ float bf2f(unsigned short h) {
  return __uint_as_float(((unsigned)h) << 16);
}
// base-4 digit reversal of a 12-bit index (involution)
__device__ __forceinline__ int rev4_12(int x) {
  unsigned r = __brev((unsigned)x) >> 20;
  return (int)(((r & 0xAAAu) >> 1) | ((r & 0x555u) << 1));
}
// LDS pad: +1 float per 32 to break power-of-2 bank patterns
#define IDX(e) ((e) + ((e) >> 5))
#define LDSN (4095 + (4095 >> 5) + 1)

// XCD-aware bijective swizzle (nwg % 8 == 0): XCD x owns contiguous logical chunk.
__device__ __forceinline__ int xcd_swz(int bid, int cpx) {
  return (bid & 7) * cpx + (bid >> 3);
}

#define BARRIER() do { asm volatile("" ::: "memory"); __builtin_amdgcn_s_barrier(); asm volatile("" ::: "memory"); } while (0)
#define WAITV6() asm volatile("s_waitcnt vmcnt(6)" ::: "memory")

// ---------------- fused prep: x bf16 round + W hi/lo transposes + twiddle table -------
// blocks [0,8192): x_q AND x_kv round (1 float4 each per thread);
// [8192,8448): W transpose; [8448,8460): twiddles.
__global__ void prep_all(const float* __restrict__ xq, const float* __restrict__ xkv,
                         unsigned short* __restrict__ qhi, unsigned short* __restrict__ khi,
                         const float* __restrict__ W0, const float* __restrict__ W1,
                         const float* __restrict__ W2, const float* __restrict__ W3,
                         unsigned short* __restrict__ WT, float2* __restrict__ TWt, int n4) {
  __shared__ float t[64][65];
  int blk = blockIdx.x;
  int tid = threadIdx.x;
  if (blk < 8192) {
    int i = blk * 256 + tid;  // i < n4
    float4 vq = ((const float4*)xq)[i];
    float4 vk = ((const float4*)xkv)[i];
    ushort4 hq, hk;
    hq.x = f2bf(vq.x); hq.y = f2bf(vq.y); hq.z = f2bf(vq.z); hq.w = f2bf(vq.w);
    hk.x = f2bf(vk.x); hk.y = f2bf(vk.y); hk.z = f2bf(vk.z); hk.w = f2bf(vk.w);
    ((ushort4*)qhi)[i] = hq;
    ((ushort4*)khi)[i] = hk;
  } else if (blk < 8448) {
    int bx = blk - 8192;
    int w = bx >> 6, tile = bx & 63;
    int k0 = (tile >> 3) << 6, n0 = (tile & 7) << 6;
    const float* W = (w == 0) ? W0 : (w == 1) ? W1 : (w == 2) ? W2 : W3;
    unsigned short* hi = WT + (size_t)(2 * w) * 262144;
    unsigned short* lo = hi + 262144;
#pragma unroll
    for (int j = 0; j < 4; ++j) {
      int i = tid + (j << 8);
      int rr = i >> 4, c4 = (i & 15) << 2;
      float4 v = *(const float4*)&W[(size_t)(k0 + rr) * 512 + n0 + c4];
      t[rr][c4 + 0] = v.x; t[rr][c4 + 1] = v.y;
      t[rr][c4 + 2] = v.z; t[rr][c4 + 3] = v.w;
    }
    __syncthreads();
#pragma unroll
    for (int j = 0; j < 4; ++j) {
      int i = tid + (j << 8);
      int nn = i >> 4, k4 = (i & 15) << 2;
      ushort4 h, l;
      float f;
      f = t[k4 + 0][nn]; h.x = f2bf(f); l.x = f2bf(f - bf2f(h.x));
      f = t[k4 + 1][nn]; h.y = f2bf(f); l.y = f2bf(f - bf2f(h.y));
      f = t[k4 + 2][nn]; h.z = f2bf(f); l.z = f2bf(f - bf2f(h.z));
      f = t[k4 + 3][nn]; h.w = f2bf(f); l.w = f2bf(f - bf2f(h.w));
      size_t o = (size_t)(n0 + nn) * 512 + k0 + k4;
      *(ushort4*)(hi + o) = h;
      *(ushort4*)(lo + o) = l;
    }
  } else {
    int r = (blk - 8448) * 256 + tid;
    if (r < 3072) {
      double a = -2.0 * 3.14159265358979323846 * (double)r / 4096.0;
      TWt[r] = make_float2((float)cos(a), (float)sin(a));
    }
  }
}

// ---------------- fused Q+K GEMM: 256^2 tile, 8-wave, 4-phase/K-tile, counted vmcnt ----
// bf16x2: 16 K-tiles (v 0..7 = Ahi*Bhi, v 8..15 = Ahi*Blo), K'=1024. Output bf16.
__global__ __launch_bounds__(512, 2)
void qk_gemm8(const unsigned short* __restrict__ AqHi, const unsigned short* __restrict__ AkvHi,
              const unsigned short* __restrict__ WT,
              const float* __restrict__ bq, const float* __restrict__ bk,
              unsigned short* __restrict__ QT, unsigned short* __restrict__ KT) {
  __shared__ __align__(16) char lds[131072];
  int tid = threadIdx.x;
  int lane = tid & 63, wv = tid >> 6;
  int wm = wv >> 2, wn = wv & 3;

  int sw = xcd_swz(blockIdx.x, 32);  // 256 wgs
  int op = sw >> 7;                  // 0 = Q, 1 = K
  int r = sw & 127;
  int m0 = (r >> 1) << 8;            // 64 M-tiles
  int n0 = (r & 1) << 8;             // 2 N-tiles

  const unsigned short* Ahi = op ? AkvHi : AqHi;
  const unsigned short* Bhi = WT + (op ? 2 * 262144 : 0);
  const unsigned short* Blo = Bhi + 262144;
  const float* bias = op ? bk : bq;
  unsigned short* C = op ? KT : QT;

  int aoff0 = ((lane & 15) << 7) + ((((lane >> 4) + 0) ^ (lane & 7)) << 4);  // ks=0
  int aoff1 = ((lane & 15) << 7) + ((((lane >> 4) + 4) ^ (lane & 7)) << 4);  // ks=1
  int src_row = tid >> 3;
  int src_col = (tid & 7) ^ (src_row & 7);

  f32x4 acc[8][4];
  const f32x4 zz = {0.f, 0.f, 0.f, 0.f};
#pragma unroll
  for (int i = 0; i < 8; ++i)
#pragma unroll
    for (int j = 0; j < 4; ++j) acc[i][j] = zz;

  auto APTR = [&](int v) {
    return Ahi + (size_t)m0 * 512 + ((v & 7) << 6);
  };
  auto BPTR = [&](int v) {
    const unsigned short* p = (v >= 8) ? Blo : Bhi;
    return p + (size_t)n0 * 512 + ((v & 7) << 6);
  };
  auto STAGE = [&](const unsigned short* gbase, int R0, int ldsOff) {
    const unsigned short* ga = gbase + (size_t)(R0 + src_row) * 512 + (src_col << 3);
    char* la = lds + ldsOff + (R0 << 7) + (wv << 10);
    __builtin_amdgcn_global_load_lds((const __attribute__((address_space(1))) void*)ga,
                                     (__attribute__((address_space(3))) void*)la, 16, 0, 0);
  };
#define RDA(o, mi, ks) (*(const bf16x8*)(lds + (o) + (wm << 14) + ((mi) << 11) + aoff##ks))
#define RDB(o, ni, ks) (*(const bf16x8*)(lds + (o) + 32768 + (wn << 13) + ((ni) << 11) + aoff##ks))
#define MFMA_PAIR(mi0, A0, A1)                                                              \
  __builtin_amdgcn_s_setprio(1);                                                            \
  _Pragma("unroll") for (int ks = 0; ks < 2; ++ks) {                                        \
    _Pragma("unroll") for (int ni = 0; ni < 4; ++ni) {                                      \
      acc[mi0][ni] = __builtin_amdgcn_mfma_f32_16x16x32_bf16(A0[ks], b[ni][ks], acc[mi0][ni], 0, 0, 0);          \
      acc[mi0 + 1][ni] = __builtin_amdgcn_mfma_f32_16x16x32_bf16(A1[ks], b[ni][ks], acc[mi0 + 1][ni], 0, 0, 0);  \
    }                                                                                       \
  }                                                                                         \
  __builtin_amdgcn_s_setprio(0)

  STAGE(BPTR(0), 0, 32768);   STAGE(BPTR(0), 64, 32768);
  STAGE(BPTR(0), 128, 32768); STAGE(BPTR(0), 192, 32768);
  STAGE(APTR(0), 0, 0);       STAGE(APTR(0), 64, 0);
  STAGE(APTR(0), 128, 0);     STAGE(APTR(0), 192, 0);
  STAGE(BPTR(1), 0, 65536 + 32768);   STAGE(BPTR(1), 64, 65536 + 32768);
  STAGE(BPTR(1), 128, 65536 + 32768); STAGE(BPTR(1), 192, 65536 + 32768);
  STAGE(APTR(1), 0, 65536);           STAGE(APTR(1), 128, 65536);
  WAITV6();
  BARRIER();

  for (int t = 0; t < 16; ++t) {
    int o = (t & 1) << 16;
    int on = o ^ 65536;
    int t1 = (t + 1 < 16) ? t + 1 : 15;
    int t2 = (t + 2 < 16) ? t + 2 : 15;
    const unsigned short* a1p = APTR(t1);
    const unsigned short* a2p = APTR(t2);
    const unsigned short* b2p = BPTR(t2);

    bf16x8 b[4][2], aA[2][2];
#pragma unroll
    for (int ni = 0; ni < 4; ++ni) { b[ni][0] = RDB(o, ni, 0); b[ni][1] = RDB(o, ni, 1); }
    aA[0][0] = RDA(o, 0, 0); aA[0][1] = RDA(o, 0, 1);
    aA[1][0] = RDA(o, 1, 0); aA[1][1] = RDA(o, 1, 1);
    STAGE(a1p, 64, on); STAGE(a1p, 192, on);
    BARRIER();
    MFMA_PAIR(0, aA[0], aA[1]);
    BARRIER();

    aA[0][0] = RDA(o, 2, 0); aA[0][1] = RDA(o, 2, 1);
    aA[1][0] = RDA(o, 3, 0); aA[1][1] = RDA(o, 3, 1);
    STAGE(b2p, 0, o + 32768); STAGE(b2p, 64, o + 32768);
    BARRIER();
    MFMA_PAIR(2, aA[0], aA[1]);
    BARRIER();

    aA[0][0] = RDA(o, 4, 0); aA[0][1] = RDA(o, 4, 1);
    aA[1][0] = RDA(o, 5, 0); aA[1][1] = RDA(o, 5, 1);
    STAGE(b2p, 128, o + 32768); STAGE(b2p, 192, o + 32768);
    BARRIER();
    MFMA_PAIR(4, aA[0], aA[1]);
    BARRIER();

    aA[0][0] = RDA(o, 6, 0); aA[0][1] = RDA(o, 6, 1);
    aA[1][0] = RDA(o, 7, 0); aA[1][1] = RDA(o, 7, 1);
    STAGE(a2p, 0, o); STAGE(a2p, 128, o);
    BARRIER();
    MFMA_PAIR(6, aA[0], aA[1]);
    WAITV6();
    BARRIER();
  }
#undef RDA
#undef RDB
#undef MFMA_PAIR

  // epilogue: bf16 C[(b*512+col)*4096 + t], ushort4 (8B) per lane
#pragma unroll
  for (int mi = 0; mi < 8; ++mi) {
    int mrow0 = m0 + (wm << 7) + (mi << 4) + ((lane >> 4) << 2);
    int bq_ = mrow0 >> 12;
    int t0 = mrow0 & 4095;
#pragma unroll
    for (int ni = 0; ni < 4; ++ni) {
      int col = n0 + (wn << 6) + (ni << 4) + (lane & 15);
      float bv = bias[col];
      f32x4 v = acc[mi][ni];
      ushort4 hv;
      hv.x = f2bf(v.x + bv); hv.y = f2bf(v.y + bv);
      hv.z = f2bf(v.z + bv); hv.w = f2bf(v.w + bv);
      *(ushort4*)&C[((size_t)(bq_ * 512 + col)) * 4096 + t0] = hv;
    }
  }
}

// ---------------- generic GEMM: V (mode 1, bf16 out) and OUT (mode 2, f32 out) ---------
// 128^2 tile, 256 thr / 4 waves (2x2), dbuf LDS + stage-next-before-compute
// (T3-min 2-phase). Reverted from the 8-wave variant (R13 regression: the
// 2-phase critical path is the per-tile drain barrier, not wave-level latency).
__global__ __launch_bounds__(256, 2)
void gemm_bf16(const unsigned short* __restrict__ Ahi,
               const unsigned short* __restrict__ Bhi,
               const float* __restrict__ bias, float* __restrict__ Cf,
               unsigned short* __restrict__ Ch, int mode) {
  __shared__ short As[2][128 * 64];
  __shared__ short Bs[2][128 * 64];
  int bx = xcd_swz(blockIdx.x, 64);  // 512 wgs
  int bm = bx >> 2, bn = bx & 3;
  int m0 = bm << 7, n0 = bn << 7;
  int tid = threadIdx.x;
  int lane = tid & 63, wv = tid >> 6;
  int wm = wv >> 1, wn = wv & 1;

  const f32x4 zz = {0.f, 0.f, 0.f, 0.f};
  f32x4 acc[4][4];
#pragma unroll
  for (int i = 0; i < 4; ++i)
#pragma unroll
    for (int j = 0; j < 4; ++j) acc[i][j] = zz;

  int srow = tid >> 3;
  int sk = (tid & 7) << 3;
  auto STAGE = [&](int ks, int buf) {
    int kb = ks << 6;
#pragma unroll
    for (int i = 0; i < 4; ++i) {
      int r = (i << 5) + srow;
      const unsigned short* ga = Ahi + (size_t)(m0 + r) * 512 + kb + sk;
      const unsigned short* gb = Bhi + (size_t)(n0 + r) * 512 + kb + sk;
      char* la = (char*)As[buf] + (i << 12) + (wv << 10);
      char* lb = (char*)Bs[buf] + (i << 12) + (wv << 10);
      __builtin_amdgcn_global_load_lds((const __attribute__((address_space(1))) void*)ga,
                                       (__attribute__((address_space(3))) void*)la, 16, 0, 0);
      __builtin_amdgcn_global_load_lds((const __attribute__((address_space(1))) void*)gb,
                                       (__attribute__((address_space(3))) void*)lb, 16, 0, 0);
    }
  };

  STAGE(0, 0);
  __syncthreads();
  for (int ks = 0; ks < 8; ++ks) {
    int buf = ks & 1;
    if (ks < 7) STAGE(ks + 1, buf ^ 1);
#pragma unroll
    for (int kk = 0; kk < 2; ++kk) {
      bf16x8 af[4], bfr[4];
      int krd = (kk << 5) + ((lane >> 4) << 3);
#pragma unroll
      for (int mi = 0; mi < 4; ++mi)
        af[mi] = *(const bf16x8*)&As[buf][((wm << 6) + (mi << 4) + (lane & 15)) * 64 + krd];
#pragma unroll
      for (int ni = 0; ni < 4; ++ni)
        bfr[ni] = *(const bf16x8*)&Bs[buf][((wn << 6) + (ni << 4) + (lane & 15)) * 64 + krd];
#pragma unroll
      for (int mi = 0; mi < 4; ++mi)
#pragma unroll
        for (int ni = 0; ni < 4; ++ni)
          acc[mi][ni] = __builtin_amdgcn_mfma_f32_16x16x32_bf16(af[mi], bfr[ni], acc[mi][ni], 0, 0, 0);
    }
    __syncthreads();  // drains ks+1 loads; protects buf reuse at ks+2
  }

#pragma unroll
  for (int mi = 0; mi < 4; ++mi) {
    int mrow0 = m0 + (wm << 6) + (mi << 4) + ((lane >> 4) << 2);
    int bq_ = mrow0 >> 12;
    int t0 = mrow0 & 4095;
#pragma unroll
    for (int ni = 0; ni < 4; ++ni) {
      int col = n0 + (wn << 6) + (ni << 4) + (lane & 15);
      float bv = bias[col];
      f32x4 v = acc[mi][ni];
      v.x += bv; v.y += bv; v.z += bv; v.w += bv;
      if (mode == 1) {
        // V layout (bf16): Ch[((b*8+h)*4096+t)*64 + d]
        size_t base = (size_t)(bq_ * 8 + (col >> 6)) * 4096;
        int d = col & 63;
        Ch[(base + t0 + 0) * 64 + d] = f2bf(v.x);
        Ch[(base + t0 + 1) * 64 + d] = f2bf(v.y);
        Ch[(base + t0 + 2) * 64 + d] = f2bf(v.z);
        Ch[(base + t0 + 3) * 64 + d] = f2bf(v.w);
      } else {
        Cf[(size_t)(mrow0 + 0) * 512 + col] = v.x;
        Cf[(size_t)(mrow0 + 1) * 512 + col] = v.y;
        Cf[(size_t)(mrow0 + 2) * 512 + col] = v.z;
        Cf[(size_t)(mrow0 + 3) * 512 + col] = v.w;
      }
    }
  }
}

// ---------------- FFT: radix-16 superstages (stage pairs fused in registers) ----------
__device__ __forceinline__ void r4(float& x0r, float& x0i, float& x1r, float& x1i,
                                   float& x2r, float& x2i, float& x3r, float& x3i,
                                   float2 w1, float2 w2, float2 w3) {
  float Ar = x0r + x2r, Ai = x0i + x2i;
  float Br = x0r - x2r, Bi = x0i - x2i;
  float Cr = x1r + x3r, Ci = x1i + x3i;
  float Dr = x1i - x3i, Di = x3r - x1r;  // -i*(x1-x3)
  x0r = Ar + Cr; x0i = Ai + Ci;
  float tr = Br + Dr, ti = Bi + Di;
  x1r = tr * w1.x - ti * w1.y; x1i = tr * w1.y + ti * w1.x;
  tr = Ar - Cr; ti = Ai - Ci;
  x2r = tr * w2.x - ti * w2.y; x2i = tr * w2.y + ti * w2.x;
  tr = Br - Dr; ti = Bi - Di;
  x3r = tr * w3.x - ti * w3.y; x3i = tr * w3.y + ti * w3.x;
}

__device__ __forceinline__ void fft16_superstages(float* re, float* im,
                                                  const float2* __restrict__ TW,
                                                  int u, bool active) {
#pragma unroll
  for (int ss = 0; ss < 3; ++ss) {
    const int lm = 10 - 4 * ss;      // 10, 6, 2
    const int m = 1 << lm;
    const int m4 = m >> 2;
    const int stw = 1 << (4 * ss);   // 1, 16, 256
    const int stw4 = stw << 2;
    if (active) {
      int jj = u & (m4 - 1);
      int g = u >> (lm - 2);
      int base = (g << (lm + 2)) + jj;
      float xr[4][4], xi[4][4];
#pragma unroll
      for (int a = 0; a < 4; ++a)
#pragma unroll
        for (int b = 0; b < 4; ++b) {
          int p = IDX(base + a * m + b * m4);
          xr[a][b] = re[p]; xi[a][b] = im[p];
        }
#pragma unroll
      for (int b = 0; b < 4; ++b) {
        int j1 = (b * m4 + jj) * stw;
        float2 w1 = TW[j1], w2 = TW[2 * j1], w3 = TW[3 * j1];
        r4(xr[0][b], xi[0][b], xr[1][b], xi[1][b], xr[2][b], xi[2][b], xr[3][b], xi[3][b], w1, w2, w3);
      }
      {
        int j2 = jj * stw4;
        float2 v1 = TW[j2], v2 = TW[2 * j2], v3 = TW[3 * j2];
#pragma unroll
        for (int a = 0; a < 4; ++a)
          r4(xr[a][0], xi[a][0], xr[a][1], xi[a][1], xr[a][2], xi[a][2], xr[a][3], xi[a][3], v1, v2, v3);
      }
#pragma unroll
      for (int a = 0; a < 4; ++a)
#pragma unroll
        for (int b = 0; b < 4; ++b) {
          int p = IDX(base + a * m + b * m4);
          re[p] = xr[a][b]; im[p] = xi[a][b];
        }
    }
    __syncthreads();
  }
}

// Packed FFT of z = q + i*k per (b,h,d) with bf16 Q/K inputs; one wg (512 thr)
// handles 4 d's as 2 rounds of 2 CONCURRENT FFTs (256 units each, wave-uniform).
// 512 wgs = 32 bh x 16 parts; NO atomics.
__global__ __launch_bounds__(512, 2)
void fft_corr(const unsigned short* __restrict__ QT, const unsigned short* __restrict__ KT,
              const float2* __restrict__ TW, float* __restrict__ PpartRe,
              float* __restrict__ PpartIm) {
  __shared__ float re[2][LDSN];
  __shared__ float im[2][LDSN];
  int wg = blockIdx.x;
  int bh = wg >> 4;
  int d0 = (wg & 15) << 2;
  int tid = threadIdx.x;
  const unsigned short* qb = QT + (size_t)bh * 64 * 4096;
  const unsigned short* kb = KT + (size_t)bh * 64 * 4096;
  float accR[8], accI[8];
#pragma unroll
  for (int j = 0; j < 8; ++j) { accR[j] = 0.f; accI[j] = 0.f; }
  for (int rr = 0; rr < 2; ++rr) {
    if (rr) __syncthreads();  // prior extraction reads done
#pragma unroll
    for (int ff = 0; ff < 2; ++ff) {
      const unsigned short* q8 = qb + (size_t)(d0 + 2 * rr + ff) * 4096;
      const unsigned short* k8 = kb + (size_t)(d0 + 2 * rr + ff) * 4096;
      uint4 qraw = *(const uint4*)(q8 + ((size_t)tid << 3));  // 8 bf16
      uint4 kraw = *(const uint4*)(k8 + ((size_t)tid << 3));
      int e = tid << 3;
      re[ff][IDX(e + 0)] = bf2f((unsigned short)(qraw.x & 0xFFFF));
      re[ff][IDX(e + 1)] = bf2f((unsigned short)(qraw.x >> 16));
      re[ff][IDX(e + 2)] = bf2f((unsigned short)(qraw.y & 0xFFFF));
      re[ff][IDX(e + 3)] = bf2f((unsigned short)(qraw.y >> 16));
      re[ff][IDX(e + 4)] = bf2f((unsigned short)(qraw.z & 0xFFFF));
      re[ff][IDX(e + 5)] = bf2f((unsigned short)(qraw.z >> 16));
      re[ff][IDX(e + 6)] = bf2f((unsigned short)(qraw.w & 0xFFFF));
      re[ff][IDX(e + 7)] = bf2f((unsigned short)(qraw.w >> 16));
      im[ff][IDX(e + 0)] = bf2f((unsigned short)(kraw.x & 0xFFFF));
      im[ff][IDX(e + 1)] = bf2f((unsigned short)(kraw.x >> 16));
      im[ff][IDX(e + 2)] = bf2f((unsigned short)(kraw.y & 0xFFFF));
      im[ff][IDX(e + 3)] = bf2f((unsigned short)(kraw.y >> 16));
      im[ff][IDX(e + 4)] = bf2f((unsigned short)(kraw.z & 0xFFFF));
      im[ff][IDX(e + 5)] = bf2f((unsigned short)(kraw.z >> 16));
      im[ff][IDX(e + 6)] = bf2f((unsigned short)(kraw.w & 0xFFFF));
      im[ff][IDX(e + 7)] = bf2f((unsigned short)(kraw.w >> 16));
    }
    __syncthreads();
    // wave-uniform FFT split: waves 0-3 -> fft 0, waves 4-7 -> fft 1
    fft16_superstages(re[tid >> 8], im[tid >> 8], TW, tid & 255, true);
#pragma unroll
    for (int ff = 0; ff < 2; ++ff) {
#pragma unroll
      for (int j = 0; j < 8; ++j) {
        int p = tid + (j << 9);
        int f = rev4_12(p);
        int fn = (4096 - f) & 4095;
        int pn = rev4_12(fn);
        float zr = re[ff][IDX(p)], zi = im[ff][IDX(p)];
        float wr = re[ff][IDX(pn)], wi = im[ff][IDX(pn)];
        float qre = 0.5f * (zr + wr), qim = 0.5f * (zi - wi);
        float kre = 0.5f * (zi + wi), kim = 0.5f * (wr - zr);
        accR[j] += qre * kre + qim * kim;   // Re(Qf*conj(Kf))
        accI[j] += qim * kre - qre * kim;   // Im(Qf*conj(Kf))
      }
    }
  }
  float* pR = PpartRe + (size_t)wg * 4096;
  float* pI = PpartIm + (size_t)wg * 4096;
#pragma unroll
  for (int j = 0; j < 8; ++j) {
    int p = tid + (j << 9);
    pR[p] = accR[j];
    pI[p] = accI[j];
  }
}

// Reduce 16 partials per (b,h) -> Psum, float4. Grid 128 = 32 bh x 4 chunks of 1024 p.
__global__ void reduce_p(const float* __restrict__ PpartRe, const float* __restrict__ PpartIm,
                         float* __restrict__ PsumRe, float* __restrict__ PsumIm) {
  int wg = blockIdx.x;
  int bh = wg >> 2;
  int p4 = ((wg & 3) << 8) + threadIdx.x;  // float4 index 0..1023
  const float4* bR = (const float4*)(PpartRe + (size_t)bh * 16 * 4096);
  const float4* bI = (const float4*)(PpartIm + (size_t)bh * 16 * 4096);
  float4 sr = make_float4(0.f, 0.f, 0.f, 0.f);
  float4 si = make_float4(0.f, 0.f, 0.f, 0.f);
#pragma unroll
  for (int part = 0; part < 16; ++part) {
    float4 a = bR[part * 1024 + p4];
    float4 b = bI[part * 1024 + p4];
    sr.x += a.x; sr.y += a.y; sr.z += a.z; sr.w += a.w;
    si.x += b.x; si.y += b.y; si.z += b.z; si.w += b.w;
  }
  ((float4*)(PsumRe + (size_t)bh * 4096))[p4] = sr;
  ((float4*)(PsumIm + (size_t)bh * 4096))[p4] = si;
}

// Inverse FFT via conj + forward DIF (radix-16); corr(tau=rev4(p)) = re[p]/(4096*64).
// Single-pass top-8: pack (value,tau) -> ordered u64 key; per-thread sort-8;
// 6-level shfl_xor butterfly with Batcher half-cleaner; final 8-list serial merge.
__global__ __launch_bounds__(512, 1)
void ifft_topk(const float* __restrict__ PsumRe, const float* __restrict__ PsumIm,
               const float2* __restrict__ TW, float* __restrict__ attnW, int* __restrict__ delays) {
  __shared__ float re[LDSN];
  __shared__ float im[LDSN];
  __shared__ unsigned long long sh[8][8];
  int bh = blockIdx.x, tid = threadIdx.x;
  int lane = tid & 63, wv = tid >> 6;
  const float4* pr4 = (const float4*)(PsumRe + (size_t)bh * 4096);
  const float4* pi4 = (const float4*)(PsumIm + (size_t)bh * 4096);
#pragma unroll
  for (int i = 0; i < 2; ++i) {
    int e4 = tid + (i << 9);
    float4 a = pr4[e4], b = pi4[e4];
    int fb = rev4_12(e4 << 2);  // rev4 of (e4*4 + j) = fb | (j<<10)
    re[IDX(fb + 0 * 1024)] = a.x; im[IDX(fb + 0 * 1024)] = -b.x;
    re[IDX(fb + 1 * 1024)] = a.y; im[IDX(fb + 1 * 1024)] = -b.y;
    re[IDX(fb + 2 * 1024)] = a.z; im[IDX(fb + 2 * 1024)] = -b.z;
    re[IDX(fb + 3 * 1024)] = a.w; im[IDX(fb + 3 * 1024)] = -b.w;
  }
  __syncthreads();
  fft16_superstages(re, im, TW, tid & 255, tid < 256);

  // build per-thread desc-sorted 8 keys (value desc, tau asc on ties)
  unsigned long long k[8];
#pragma unroll
  for (int i = 0; i < 8; ++i) {
    int p = tid + (i << 9);
    float v = re[IDX(p)];
    int tau = rev4_12(p);
    unsigned u = __float_as_uint(v);
    unsigned s = u ^ (unsigned)(((int)u >> 31) | 0x80000000);  // order-preserving map
    k[i] = ((unsigned long long)s << 12) | (unsigned)(4095 - tau);
  }
#define CSWAP(a, b) { if (k[a] < k[b]) { unsigned long long t_ = k[a]; k[a] = k[b]; k[b] = t_; } }
  // insertion network (28 comparators), descending
#pragma unroll
  for (int i = 1; i < 8; ++i)
#pragma unroll
    for (int j = 8 - 1; j >= 1; --j)
      if (j <= i) CSWAP(j - 1, j);
  // butterfly merge across 64 lanes: keep top-8 of pairwise unions
#pragma unroll
  for (int off = 1; off < 64; off <<= 1) {
    unsigned long long b[8];
#pragma unroll
    for (int i = 0; i < 8; ++i)
      b[i] = (unsigned long long)__shfl_xor((long long)k[i], off);
#pragma unroll
    for (int i = 0; i < 8; ++i) {
      unsigned long long m = b[7 - i];        // half-cleaner: max(A[i], B[7-i])
      k[i] = (k[i] > m) ? k[i] : m;
    }
    // bitonic clean (descending), distances 4, 2, 1
#pragma unroll
    for (int d = 4; d > 0; d >>= 1)
#pragma unroll
      for (int i = 0; i < 8; ++i)
        if ((i & d) == 0 && (i ^ d) < 8) CSWAP(i, i + d);
  }
#undef CSWAP
  if (lane == 0) {
#pragma unroll
    for (int i = 0; i < 8; ++i) sh[wv][i] = k[i];
  }
  __syncthreads();
  if (tid == 0) {
    const float SC = 1.0f / 262144.0f;  // 1/(L*Dh)
    int idx[8] = {0, 0, 0, 0, 0, 0, 0, 0};
    float topv[8]; int topi[8];
#pragma unroll
    for (int pass = 0; pass < 8; ++pass) {
      int bw = 0;
      unsigned long long bk = sh[0][idx[0]];
#pragma unroll
      for (int w = 1; w < 8; ++w) {
        unsigned long long c = sh[w][idx[w]];
        if (c > bk) { bk = c; bw = w; }
      }
      idx[bw]++;
      unsigned s = (unsigned)(bk >> 12);
      unsigned u = (s & 0x80000000u) ? (s ^ 0x80000000u) : ~s;
      topv[pass] = __uint_as_float(u) * SC;
      topi[pass] = 4095 - (int)(bk & 4095u);
    }
    float mx = topv[0];  // pass 0 = global max
    float ex[8], ssum = 0.f;
    for (int q = 0; q < 8; ++q) { ex[q] = expf(topv[q] - mx); ssum += ex[q]; }
    float inv = 1.0f / ssum;
    for (int q = 0; q < 8; ++q) {
      attnW[bh * 8 + q] = ex[q] * inv;
      delays[bh * 8 + q] = topi[q];
    }
  }
}

// out[b,h,t,:] = sum_k attn_k * V[b,h,(t-d_k)%L,:] (V bf16); write bf16 A for OUT gemm.
// Grid 4096 = 32 bh x 128 t-chunks of 32; thread handles 8 d's (16B loads/stores).
__global__ void gather_av(const unsigned short* __restrict__ Vh, const float* __restrict__ attnW,
                          const int* __restrict__ delays, unsigned short* __restrict__ Ahi) {
  int blk = blockIdx.x;
  int bh = blk >> 7, tb = blk & 127;
  int tid = threadIdx.x;
  int tt = tid >> 3, d8 = tid & 7;
  int t = (tb << 5) + tt;
  const unsigned short* Vb = Vh + (size_t)bh * 4096 * 64 + (d8 << 3);
  float w[8]; int dl[8];
#pragma unroll
  for (int kk = 0; kk < 8; ++kk) { w[kk] = attnW[bh * 8 + kk]; dl[kk] = delays[bh * 8 + kk]; }
  float a0 = 0.f, a1 = 0.f, a2 = 0.f, a3 = 0.f, a4 = 0.f, a5 = 0.f, a6 = 0.f, a7 = 0.f;
#pragma unroll
  for (int kk = 0; kk < 8; ++kk) {
    int row = (t - dl[kk]) & 4095;
    uint4 raw = *(const uint4*)(Vb + row * 64);
    float wk = w[kk];
    a0 += wk * bf2f((unsigned short)(raw.x & 0xFFFF));
    a1 += wk * bf2f((unsigned short)(raw.x >> 16));
    a2 += wk * bf2f((unsigned short)(raw.y & 0xFFFF));
    a3 += wk * bf2f((unsigned short)(raw.y >> 16));
    a4 += wk * bf2f((unsigned short)(raw.z & 0xFFFF));
    a5 += wk * bf2f((unsigned short)(raw.z >> 16));
    a6 += wk * bf2f((unsigned short)(raw.w & 0xFFFF));
    a7 += wk * bf2f((unsigned short)(raw.w >> 16));
  }
  int b = bh >> 3, h = bh & 7;
  size_t o = ((size_t)((b << 12) + t)) * 512 + (h << 6) + (d8 << 3);
  uint4 out;
  out.x = (unsigned)f2bf(a0) | ((unsigned)f2bf(a1) << 16);
  out.y = (unsigned)f2bf(a2) | ((unsigned)f2bf(a3) << 16);
  out.z = (unsigned)f2bf(a4) | ((unsigned)f2bf(a5) << 16);
  out.w = (unsigned)f2bf(a6) | ((unsigned)f2bf(a7) << 16);
  *(uint4*)(Ahi + o) = out;
}

// ---------------- orchestration ----------------
extern "C" void kernel_launch(void* const* d_in, const int* in_sizes, int n_in,
                              void* d_out, int out_size, void* d_ws, size_t ws_size,
                              hipStream_t stream) {
  (void)in_sizes; (void)n_in; (void)out_size; (void)ws_size;
  const float* x_q = (const float*)d_in[0];
  const float* x_kv = (const float*)d_in[1];
  const float* Wq = (const float*)d_in[2];
  const float* bq = (const float*)d_in[3];
  const float* Wk = (const float*)d_in[4];
  const float* bk = (const float*)d_in[5];
  const float* Wv = (const float*)d_in[6];
  const float* bv = (const float*)d_in[7];
  const float* Wo = (const float*)d_in[8];
  const float* bo = (const float*)d_in[9];
  float* out = (float*)d_out;
  char* ws = (char*)d_ws;

  // workspace layout (~137.1 MiB)
  unsigned short* AqHi  = (unsigned short*)(ws + 0 * MiB);
  unsigned short* Vbuf16 = (unsigned short*)(ws + 0 * MiB);  // after qk_gemm8
  unsigned short* AkvHi = (unsigned short*)(ws + 36 * MiB);
  float* PpartRe = (float*)(ws + 36 * MiB);                  // after v_gemm
  float* PpartIm = (float*)(ws + 52 * MiB);
  unsigned short* Aattn = (unsigned short*)(ws + 36 * MiB);  // after reduce_p
  unsigned short* WTb   = (unsigned short*)(ws + 68 * MiB);
  unsigned short* QT    = (unsigned short*)(ws + 72 * MiB);
  unsigned short* KT    = (unsigned short*)(ws + 104 * MiB);
  float* PsumRe = (float*)(ws + 72 * MiB);
  float* PsumIm = (float*)(ws + 73 * MiB);
  float* attnW = (float*)(ws + 137 * MiB);
  int*   delays = (int*)(ws + 137 * MiB + 4096);
  float2* TW   = (float2*)(ws + 137 * MiB + 8192);

  int n4 = (16384 * 512) / 4;
  prep_all<<<dim3(8460), dim3(256), 0, stream>>>(x_q, x_kv, AqHi, AkvHi,
                                                 Wq, Wk, Wv, Wo, WTb, TW, n4);

  // Q and K projections fused, 256^2 8-phase bf16x2 (256 wgs x 512 thr).
  qk_gemm8<<<dim3(256), dim3(512), 0, stream>>>(AqHi, AkvHi, WTb, bq, bk, QT, KT);
  gemm_bf16<<<dim3(512), dim3(256), 0, stream>>>(AkvHi, WTb + 4 * 262144, bv, nullptr, Vbuf16, 1);

  fft_corr<<<dim3(512), dim3(512), 0, stream>>>(QT, KT, TW, PpartRe, PpartIm);
  reduce_p<<<dim3(128), dim3(256), 0, stream>>>(PpartRe, PpartIm, PsumRe, PsumIm);
  ifft_topk<<<dim3(32), dim3(512), 0, stream>>>(PsumRe, PsumIm, TW, attnW, delays);
  gather_av<<<dim3(4096), dim3(256), 0, stream>>>(Vbuf16, attnW, delays, Aattn);

  // out = gathered @ Wo + bo (plain bf16 -> f32 out)
  gemm_bf16<<<dim3(512), dim3(256), 0, stream>>>(Aattn, WTb + 6 * 262144, bo, out, nullptr, 2);
}